// Round 17
// baseline (16205.840 us; speedup 1.0000x reference)
//
#include <hip/hip_runtime.h>
#include <math.h>

#define B_   64
#define S_   512
#define IN_  512
#define H_   1024
#define WLK_ (H_ + 128)
#define NBLK 256
#define NTHR 512
#define HALF 128

typedef unsigned long long ull;
typedef int   i32x4 __attribute__((ext_vector_type(4)));
typedef float f32x4 __attribute__((ext_vector_type(4)));

// CK-style raw buffer load (compiler-scheduled, vmcnt-tracked). cachepolicy=16
// -> SC1 device-scope, MALL-served (R8/R16-proven agent-coherent on gfx950).
__device__ f32x4 llvm_amdgcn_raw_buffer_load_v4f32(i32x4 srsrc, int voffset,
                                                   int soffset, int cachepolicy)
    __asm("llvm.amdgcn.raw.buffer.load.v4f32");

__device__ __forceinline__ i32x4 mkrsrc(const void* p) {
    union { const void* p; unsigned u[2]; } a; a.p = p;
    i32x4 r;
    r.x = (int)a.u[0];
    r.y = (int)a.u[1];
    r.z = -1;
    r.w = 0x00020000;
    return r;
}

// ---- static device scratch ----
__device__ float g_xT[(size_t)S_ * IN_ * B_];      // [s][k][b]
__device__ float g_h0T[H_ * B_];                   // [k][b]
__device__ float g_hT[2][H_ * B_];                 // [k][b] (coherent)
__device__ float g_hhatT[H_ * B_];                 // [j][b] (coherent)
__device__ float g_zprojT[H_ * B_];                // [j][b] incl b_lin
__device__ float g_WihP[(size_t)HALF * IN_ * 24];  // [cg][k][c] packed Wih
__device__ float g_WlinP[(size_t)HALF * H_ * 8];   // [cg][k][c] packed Wlin_h
__device__ unsigned g_barH[2][2 * S_][1024];       // per-half, 32 ctrs 128B apart

// Coherent 8B store (R7-proven). Model: step = serial latency chain dominated
// by per-thread outstanding MALL requests (R15->R16: halving requests -> -17%).
// This round halves again via batch-split (32-b slices). LESSONS embedded:
// no weight composition (R13), no deep named-reg pipelines (R8/R9), no
// plain-load cross-CU staging (R11), no extra waves (R12).
__device__ __forceinline__ void coh_store2(float* p, float x, float y) {
    union { float2 f; ull u; } v; v.f = make_float2(x, y);
    __hip_atomic_store((ull*)p, v.u, __ATOMIC_RELAXED, __HIP_MEMORY_SCOPE_AGENT);
}

// ---------------- prologue 1: transpose inputs [B][S][IN] -> xT [S][IN][B] ----
__global__ void pre_transpose_x(const float* __restrict__ in) {
    __shared__ float lds[64][65];
    int s  = blockIdx.x >> 3;
    int k0 = (blockIdx.x & 7) << 6;
    int tid = threadIdx.x;
    int kk = tid & 63, bq = tid >> 6;
    for (int b = bq; b < 64; b += 4)
        lds[kk][b] = in[((size_t)b * S_ + s) * IN_ + k0 + kk];
    __syncthreads();
    int bb = tid & 63, kq = tid >> 6;
    for (int k = kq; k < 64; k += 4)
        g_xT[((size_t)s * IN_ + k0 + k) * B_ + bb] = lds[k][bb];
}

// ---------------- prologue 2: z_projT (incl b_lin), h0T, zero barriers ------
__global__ void pre_misc(const float* __restrict__ z, const float* __restrict__ Wlin,
                         const float* __restrict__ blin, const float* __restrict__ h0) {
    __shared__ float zT[128][65];
    int j = blockIdx.x;      // 0..1023 == 2*S_ rows
    int b = threadIdx.x;     // 0..63
    for (int i = 0; i < 128; ++i) {
        int idx = b + (i << 6);
        zT[idx & 127][idx >> 7] = z[idx];
    }
    __syncthreads();
    float acc = blin[j];
    const float* w = Wlin + (size_t)j * WLK_ + H_;
    for (int k = 0; k < 128; ++k)
        acc = fmaf(zT[k][b], w[k], acc);
    g_zprojT[j * 64 + b] = acc;
    g_h0T[j * 64 + b]    = h0[(size_t)b * H_ + j];
    for (int i = b; i < 1024; i += 64) {
        g_barH[0][j][i] = 0;
        g_barH[1][j][i] = 0;
    }
}

// ---------------- prologue 3: pack Wih [cg][k][24], Wlin_h [cg][k][8] -------
__global__ void pack_w(const float* __restrict__ Wih, const float* __restrict__ Wlin) {
    int cg = blockIdx.x, tid = threadIdx.x;
    for (int c = 0; c < 24; ++c) {
        const float* src = Wih + (size_t)((c >> 3) * H_ + (cg << 3) + (c & 7)) * IN_;
        float* dst = g_WihP + (size_t)cg * IN_ * 24 + c;
        for (int k = tid; k < IN_; k += 256) dst[(size_t)k * 24] = src[k];
    }
    for (int c = 0; c < 8; ++c) {
        const float* src = Wlin + (size_t)((cg << 3) + c) * WLK_;
        float* dst = g_WlinP + (size_t)cg * H_ * 8 + c;
        for (int k = tid; k < H_; k += 256) dst[(size_t)k * 8] = src[k];
    }
}

#define F4(AC, WS) AC.x=fmaf(WS,a.x,AC.x); AC.y=fmaf(WS,a.y,AC.y); AC.z=fmaf(WS,a.z,AC.z); AC.w=fmaf(WS,a.w,AC.w);

#define RED3(V) \
    V.x += __shfl_xor(V.x,8);  V.y += __shfl_xor(V.y,8);  \
    V.z += __shfl_xor(V.z,8);  V.w += __shfl_xor(V.w,8);  \
    V.x += __shfl_xor(V.x,16); V.y += __shfl_xor(V.y,16); \
    V.z += __shfl_xor(V.z,16); V.w += __shfl_xor(V.w,16); \
    V.x += __shfl_xor(V.x,32); V.y += __shfl_xor(V.y,32); \
    V.z += __shfl_xor(V.z,32); V.w += __shfl_xor(V.w,32);

// ---- gi 12-col slice over K=512, 32-b: x + packed Wih from L2 (plain loads)
template<int C0>
__device__ __forceinline__ void gi12(const float* __restrict__ xsrc, int b0,
                                     const float* __restrict__ wihp,
                                     const float* bias_l, float* dst,
                                     float* red, int tid) {
    const int bq = tid & 7, kq = tid >> 3;
    const int wv = tid >> 6, ln = tid & 63;
    const float* ap = xsrc + (kq << 6) + b0 + (bq << 2);
    const float* wp = wihp + kq * 24 + C0;
    f32x4 acc[12];
    #pragma unroll
    for (int c = 0; c < 12; ++c) acc[c] = (f32x4){0.f,0.f,0.f,0.f};
    #pragma unroll 4
    for (int i = 0; i < 8; ++i) {
        f32x4 a  = *(const f32x4*)ap;  ap += 64 * 64;
        f32x4 w0 = *(const f32x4*)(wp + 0);
        f32x4 w1 = *(const f32x4*)(wp + 4);
        f32x4 w2 = *(const f32x4*)(wp + 8);  wp += 64 * 24;
        F4(acc[0],w0.x) F4(acc[1],w0.y) F4(acc[2],w0.z)  F4(acc[3],w0.w)
        F4(acc[4],w1.x) F4(acc[5],w1.y) F4(acc[6],w1.z)  F4(acc[7],w1.w)
        F4(acc[8],w2.x) F4(acc[9],w2.y) F4(acc[10],w2.z) F4(acc[11],w2.w)
    }
    #pragma unroll
    for (int c = 0; c < 12; ++c) {
        f32x4 v = acc[c];
        RED3(v)
        if (ln < 8) *(f32x4*)&red[(wv * 12 + c) * 32 + (ln << 2)] = v;
    }
    __syncthreads();
    if (tid < 384) {
        int c = tid >> 5, b = tid & 31;
        float s = bias_l[C0 + c];
        #pragma unroll
        for (int w = 0; w < 8; ++w) s += red[(w * 12 + c) * 32 + b];
        dst[(C0 + c) * 32 + b] = s;
    }
}

// global barrier wait (per half): 32 counters x 4 arrivals, parallel poll
__device__ __forceinline__ void gbar_wait(int bh, int slot, int tid) {
    if (tid < 64) {
        for (;;) {
            unsigned c = __hip_atomic_load(&g_barH[bh][slot][(tid & 31) << 5],
                                           __ATOMIC_RELAXED, __HIP_MEMORY_SCOPE_AGENT);
            if (__all(c >= 4u)) break;
            __builtin_amdgcn_s_sleep(1);
        }
    }
    __syncthreads();
    asm volatile("" ::: "memory");
}

// ---------------- persistent recurrence kernel ------------------------------
// 256 blocks x 512 threads; block = (cg in [0,128), bh in {0,1}) owning
// 8 h_hat cols + 24 gh cols for 32 batch elems. 16 sc1 reqs/thread/phase.
__launch_bounds__(NTHR, 1)
__global__ void skipgru_bs(const float* __restrict__ Whh, const float* __restrict__ bhh_g,
                           const float* __restrict__ bih_g, float* __restrict__ out) {
    __shared__ float wH[H_ * 24];        // 96 KB  Whh cols [k][c] (2-way cflt: free)
    __shared__ float red[8 * 12 * 32];   // 12 KB
    __shared__ float gh_l[24 * 32];
    __shared__ float gi_a[24 * 32];
    __shared__ float gi_b[24 * 32];
    __shared__ float hh_l[8 * 32];
    __shared__ float hn_l[8 * 32];
    __shared__ float zp_l[8 * 32];
    __shared__ float bhh_l[24];
    __shared__ float bih_l[24];

    const int tid = threadIdx.x;
    const int cg  = blockIdx.x >> 1;
    const int bh  = blockIdx.x & 1;
    const int jb8 = cg << 3;
    const int b0  = bh << 5;
    const int bq  = tid & 7;
    const int kq  = tid >> 3;            // 0..63
    const int wv  = tid >> 6, ln = tid & 63;
    const int barctr = (cg & 31) << 5;
    const float* wihp  = g_WihP  + (size_t)cg * IN_ * 24;
    const float* wlinp = g_WlinP + (size_t)cg * H_ * 8;

    // ---- stage Whh into LDS ----
    for (int c = 0; c < 24; ++c) {
        const float* src = Whh + (size_t)((c >> 3) * H_ + jb8 + (c & 7)) * H_;
        for (int k = tid; k < H_; k += NTHR) wH[k * 24 + c] = src[k];
    }
    if (tid < 256) zp_l[tid] = g_zprojT[(jb8 + (tid >> 5)) * 64 + b0 + (tid & 31)];
    if (tid < 24) {
        bhh_l[tid] = bhh_g[(tid >> 3) * H_ + jb8 + (tid & 7)];
        bih_l[tid] = bih_g[(tid >> 3) * H_ + jb8 + (tid & 7)];
    }
    __syncthreads();

    // ---- gi(0) ----
    gi12<0>(g_xT, b0, wihp, bih_l, gi_a, red, tid);
    __syncthreads();
    gi12<12>(g_xT, b0, wihp, bih_l, gi_a, red, tid);
    __syncthreads();

    const i32x4 rs_hhat = mkrsrc(g_hhatT);
    const i32x4 rs_h0   = mkrsrc(g_h0T);
    const i32x4 rs_ha   = mkrsrc(g_hT[0]);
    const i32x4 rs_hb   = mkrsrc(g_hT[1]);

    for (int t = 0; t < S_; ++t) {
        const i32x4 rs_h = (t == 0) ? rs_h0 : ((t & 1) ? rs_hb : rs_ha);
        const float* gi_cur = (t & 1) ? gi_b : gi_a;
        float*       gi_nxt = (t & 1) ? gi_a : gi_b;
        const float* xnxt = g_xT + (size_t)(t + 1) * IN_ * B_;

        // ---- P1: h_hat 8 cols x 32 b, K=1024; h via sc1 (16 reqs/thread),
        //      Wlin from packed L2 ----
        {
            int voff = ((kq << 6) + b0 + (bq << 2)) << 2;
            const float* wp = wlinp + kq * 8;
            f32x4 acc[8];
            #pragma unroll
            for (int c = 0; c < 8; ++c) acc[c] = (f32x4){0.f,0.f,0.f,0.f};
            #pragma unroll 4
            for (int i = 0; i < 16; ++i) {
                f32x4 a = llvm_amdgcn_raw_buffer_load_v4f32(rs_h, voff, 0, 16);
                voff += 16384;
                f32x4 w0 = *(const f32x4*)(wp + 0);
                f32x4 w1 = *(const f32x4*)(wp + 4);  wp += 64 * 8;
                F4(acc[0],w0.x) F4(acc[1],w0.y) F4(acc[2],w0.z) F4(acc[3],w0.w)
                F4(acc[4],w1.x) F4(acc[5],w1.y) F4(acc[6],w1.z) F4(acc[7],w1.w)
            }
            #pragma unroll
            for (int c = 0; c < 8; ++c) {
                f32x4 v = acc[c];
                RED3(v)
                if (ln < 8) *(f32x4*)&red[(wv * 8 + c) * 32 + (ln << 2)] = v;
            }
        }
        __syncthreads();
        if (tid < 256) {
            int c = tid >> 5, b = tid & 31;
            float s = zp_l[tid];
            #pragma unroll
            for (int w = 0; w < 8; ++w) s += red[(w * 8 + c) * 32 + b];
            hh_l[tid] = s;
        }
        __syncthreads();
        if (tid < 128) {
            int c = tid >> 4, pb = (tid & 15) << 1;
            coh_store2(&g_hhatT[(jb8 + c) * 64 + b0 + pb],
                       hh_l[c * 32 + pb], hh_l[c * 32 + pb + 1]);
        }
        __syncthreads();   // vmcnt(0) drain before arrive

        // ---- arrive A ----
        if (tid == 0)
            __hip_atomic_fetch_add(&g_barH[bh][2 * t][barctr], 1u, __ATOMIC_RELAXED, __HIP_MEMORY_SCOPE_AGENT);

        // ---- gi(t+1) cols 0-11, hidden under A ----
        if (t + 1 < S_)
            gi12<0>(xnxt, b0, wihp, bih_l, gi_nxt, red, tid);

        // ---- wait A ----
        gbar_wait(bh, 2 * t, tid);

        // ---- P2: gh 24 cols x 32 b, K=1024; h_hat via sc1 (16 reqs/thread),
        //      Whh from LDS ----
        {
            int voff = ((kq << 6) + b0 + (bq << 2)) << 2;
            const float* wp = wH + kq * 24;
            f32x4 acc[24];
            #pragma unroll
            for (int c = 0; c < 24; ++c) acc[c] = (f32x4){0.f,0.f,0.f,0.f};
            #pragma unroll 4
            for (int i = 0; i < 16; ++i) {
                f32x4 a = llvm_amdgcn_raw_buffer_load_v4f32(rs_hhat, voff, 0, 16);
                voff += 16384;
                f32x4 w0 = *(const f32x4*)(wp + 0);
                f32x4 w1 = *(const f32x4*)(wp + 4);
                f32x4 w2 = *(const f32x4*)(wp + 8);
                f32x4 w3 = *(const f32x4*)(wp + 12);
                f32x4 w4 = *(const f32x4*)(wp + 16);
                f32x4 w5 = *(const f32x4*)(wp + 20);  wp += 64 * 24;
                F4(acc[0],w0.x)  F4(acc[1],w0.y)  F4(acc[2],w0.z)  F4(acc[3],w0.w)
                F4(acc[4],w1.x)  F4(acc[5],w1.y)  F4(acc[6],w1.z)  F4(acc[7],w1.w)
                F4(acc[8],w2.x)  F4(acc[9],w2.y)  F4(acc[10],w2.z) F4(acc[11],w2.w)
                F4(acc[12],w3.x) F4(acc[13],w3.y) F4(acc[14],w3.z) F4(acc[15],w3.w)
                F4(acc[16],w4.x) F4(acc[17],w4.y) F4(acc[18],w4.z) F4(acc[19],w4.w)
                F4(acc[20],w5.x) F4(acc[21],w5.y) F4(acc[22],w5.z) F4(acc[23],w5.w)
            }
            #pragma unroll
            for (int h = 0; h < 2; ++h) {
                #pragma unroll
                for (int c = 0; c < 12; ++c) {
                    f32x4 v = acc[h * 12 + c];
                    RED3(v)
                    if (ln < 8) *(f32x4*)&red[(wv * 12 + c) * 32 + (ln << 2)] = v;
                }
                __syncthreads();
                if (tid < 384) {
                    int c = tid >> 5, b = tid & 31;
                    float s = bhh_l[h * 12 + c];
                    #pragma unroll
                    for (int w = 0; w < 8; ++w) s += red[(w * 12 + c) * 32 + b];
                    gh_l[(h * 12 + c) * 32 + b] = s;
                }
                __syncthreads();
            }
        }

        // ---- gates (threads 0..255: 8 cols x 32 b) ----
        if (tid < 256) {
            int j = tid >> 5, b = tid & 31;
            float hh = hh_l[tid];
            float hr = gh_l[j * 32 + b];
            float hz = gh_l[(8 + j) * 32 + b];
            float hn = gh_l[(16 + j) * 32 + b];
            float ir = gi_cur[j * 32 + b];
            float iz = gi_cur[(8 + j) * 32 + b];
            float in_ = gi_cur[(16 + j) * 32 + b];
            float r = 1.f / (1.f + expf(-(ir + hr)));
            float u = 1.f / (1.f + expf(-(iz + hz)));
            float n = tanhf(in_ + r * hn);
            float v = (1.f - u) * n + u * hh;
            hn_l[tid] = v;
        }
        __syncthreads();
        if (tid < 128) {
            int c = tid >> 4, pb = (tid & 15) << 1;
            coh_store2(&g_hT[(t + 1) & 1][(jb8 + c) * 64 + b0 + pb],
                       hn_l[c * 32 + pb], hn_l[c * 32 + pb + 1]);
        }
        __syncthreads();   // vmcnt(0) drain before arrive

        // ---- arrive B ----
        if (tid == 0)
            __hip_atomic_fetch_add(&g_barH[bh][2 * t + 1][barctr], 1u, __ATOMIC_RELAXED, __HIP_MEMORY_SCOPE_AGENT);

        // ---- out write + gi(t+1) cols 12-23, hidden under B ----
        if (tid < 256) {
            int j = tid >> 5, b = tid & 31;
            float v = hn_l[tid];
            out[((size_t)(b0 + b) * S_ + t) * H_ + jb8 + j] = v;
            if (t == S_ - 1)
                out[(size_t)B_ * S_ * H_ + (size_t)(b0 + b) * H_ + jb8 + j] = v;
        }
        if (t + 1 < S_)
            gi12<12>(xnxt, b0, wihp, bih_l, gi_nxt, red, tid);

        // ---- wait B ----
        gbar_wait(bh, 2 * t + 1, tid);
    }
}

extern "C" void kernel_launch(void* const* d_in, const int* in_sizes, int n_in,
                              void* d_out, int out_size, void* d_ws, size_t ws_size,
                              hipStream_t stream) {
    const float* inputs = (const float*)d_in[0];
    const float* h0     = (const float*)d_in[1];
    const float* z      = (const float*)d_in[2];
    const float* Wlin   = (const float*)d_in[3];
    const float* blin   = (const float*)d_in[4];
    const float* Wih    = (const float*)d_in[5];
    const float* bih    = (const float*)d_in[6];
    const float* Whh    = (const float*)d_in[7];
    const float* bhh    = (const float*)d_in[8];
    float* out = (float*)d_out;

    hipLaunchKernelGGL(pre_transpose_x, dim3(S_ * 8), dim3(256), 0, stream, inputs);
    hipLaunchKernelGGL(pre_misc, dim3(H_), dim3(64), 0, stream, z, Wlin, blin, h0);
    hipLaunchKernelGGL(pack_w, dim3(HALF), dim3(256), 0, stream, Wih, Wlin);
    hipLaunchKernelGGL(skipgru_bs, dim3(NBLK), dim3(NTHR), 0, stream,
                       Whh, bhh, bih, out);
}

// Round 18
// 9292.699 us; speedup vs baseline: 1.7439x; 1.7439x over previous
//
#include <hip/hip_runtime.h>
#include <math.h>

#define B_   64
#define S_   512
#define IN_  512
#define H_   1024
#define WLK_ (H_ + 128)
#define NBLK 256
#define NTHR 512

typedef unsigned long long ull;
typedef int   i32x4 __attribute__((ext_vector_type(4)));
typedef float f32x4 __attribute__((ext_vector_type(4)));

// CK-style raw buffer load intrinsic (compiler-scheduled, vmcnt-tracked).
// cachepolicy=16 -> SC1: device-scope, MALL-served (R8/R16-proven coherent).
__device__ f32x4 llvm_amdgcn_raw_buffer_load_v4f32(i32x4 srsrc, int voffset,
                                                   int soffset, int cachepolicy)
    __asm("llvm.amdgcn.raw.buffer.load.v4f32");

__device__ __forceinline__ i32x4 mkrsrc(const void* p) {
    union { const void* p; unsigned u[2]; } a; a.p = p;
    i32x4 r;
    r.x = (int)a.u[0];
    r.y = (int)a.u[1];
    r.z = -1;
    r.w = 0x00020000;
    return r;
}

// ---- static device scratch ----
__device__ float g_xT[(size_t)S_ * IN_ * B_];   // [s][k][b]
__device__ float g_h0T[H_ * B_];                // [k][b]
__device__ float g_hT[2][H_ * B_];              // [k][b]  (coherent)
__device__ float g_hhatT[H_ * B_];              // [j][b]  (coherent)
__device__ float g_zprojT[H_ * B_];             // [j][b] includes b_lin
__device__ unsigned g_bar[2 * S_][2048];        // 64 counters/slot, 128B apart

// Coherent 8B store (R7-proven). LESSONS: weight composition numerically
// fatal (R13); deep named-reg asm pipelines spill (R8/R9); plain-load
// cross-CU staging races (R11); more waves hurt (R12); batch-split hurts
// (R14/R17: L2 weight streams + LDS conflicts + extra reduces swamp the
// request-count saving). R16 structure is the right dataflow; this round
// only deepens P2's load pipeline and shortens the barrier RMW chain.
__device__ __forceinline__ void coh_store2(float* p, float x, float y) {
    union { float2 f; ull u; } v; v.f = make_float2(x, y);
    __hip_atomic_store((ull*)p, v.u, __ATOMIC_RELAXED, __HIP_MEMORY_SCOPE_AGENT);
}

// ---------------- prologue 1: transpose inputs [B][S][IN] -> xT [S][IN][B] ----
__global__ void pre_transpose_x(const float* __restrict__ in) {
    __shared__ float lds[64][65];
    int s  = blockIdx.x >> 3;
    int k0 = (blockIdx.x & 7) << 6;
    int tid = threadIdx.x;
    int kk = tid & 63, bq = tid >> 6;
    for (int b = bq; b < 64; b += 4)
        lds[kk][b] = in[((size_t)b * S_ + s) * IN_ + k0 + kk];
    __syncthreads();
    int bb = tid & 63, kq = tid >> 6;
    for (int k = kq; k < 64; k += 4)
        g_xT[((size_t)s * IN_ + k0 + k) * B_ + bb] = lds[k][bb];
}

// ---------------- prologue 2: z_projT (incl b_lin), h0T, zero barriers ------
__global__ void pre_misc(const float* __restrict__ z, const float* __restrict__ Wlin,
                         const float* __restrict__ blin, const float* __restrict__ h0) {
    __shared__ float zT[128][65];
    int j = blockIdx.x;      // 0..1023 == 2*S_ rows exactly
    int b = threadIdx.x;     // 0..63
    for (int i = 0; i < 128; ++i) {
        int idx = b + (i << 6);
        zT[idx & 127][idx >> 7] = z[idx];
    }
    __syncthreads();
    float acc = blin[j];
    const float* w = Wlin + (size_t)j * WLK_ + H_;
    for (int k = 0; k < 128; ++k)
        acc = fmaf(zT[k][b], w[k], acc);
    g_zprojT[j * 64 + b] = acc;
    g_h0T[j * 64 + b]    = h0[(size_t)b * H_ + j];
    for (int i = b; i < 2048; i += 64)
        g_bar[j][i] = 0;
}

#define F4(AC, WS) AC.x=fmaf(WS,a.x,AC.x); AC.y=fmaf(WS,a.y,AC.y); AC.z=fmaf(WS,a.z,AC.z); AC.w=fmaf(WS,a.w,AC.w);

// 12-col GEMM over K=512, plain cached loads (read-only x) — for gi(0)
__device__ __forceinline__ void gemm12n(const float* __restrict__ src,
                                        const float* wl,
                                        const float* bias_l, float* dst,
                                        float* red, int tid) {
    const int bq = tid & 15, kq = tid >> 4;
    const int wv = tid >> 6, ln = tid & 63;
    const float* ap = src + (kq << 6) + (bq << 2);
    const float* wp = wl + kq * 12;
    f32x4 acc[12];
    #pragma unroll
    for (int c = 0; c < 12; ++c) acc[c] = (f32x4){0.f,0.f,0.f,0.f};
    #pragma unroll 4
    for (int i = 0; i < 16; ++i) {
        f32x4 a  = *(const f32x4*)ap;  ap += 32 * 64;
        f32x4 w0 = *(const f32x4*)(wp + 0);
        f32x4 w1 = *(const f32x4*)(wp + 4);
        f32x4 w2 = *(const f32x4*)(wp + 8);  wp += 32 * 12;
        F4(acc[0],w0.x) F4(acc[1],w0.y) F4(acc[2],w0.z)  F4(acc[3],w0.w)
        F4(acc[4],w1.x) F4(acc[5],w1.y) F4(acc[6],w1.z)  F4(acc[7],w1.w)
        F4(acc[8],w2.x) F4(acc[9],w2.y) F4(acc[10],w2.z) F4(acc[11],w2.w)
    }
    #pragma unroll
    for (int c = 0; c < 12; ++c) {
        f32x4 v = acc[c];
        v.x += __shfl_xor(v.x,16); v.y += __shfl_xor(v.y,16);
        v.z += __shfl_xor(v.z,16); v.w += __shfl_xor(v.w,16);
        v.x += __shfl_xor(v.x,32); v.y += __shfl_xor(v.y,32);
        v.z += __shfl_xor(v.z,32); v.w += __shfl_xor(v.w,32);
        if (ln < 16) *(f32x4*)&red[(wv * 12 + c) * 64 + (ln << 2)] = v;
    }
    __syncthreads();
    for (int o = tid; o < 768; o += NTHR) {
        int c = o >> 6, b = o & 63;
        float s = bias_l[c];
        #pragma unroll
        for (int w = 0; w < 8; ++w) s += red[(w * 12 + c) * 64 + b];
        dst[o] = s;
    }
}

// 12-col GEMM over K=1024, 16B sc1 buffer loads — unroll 8 (deep pipeline)
__device__ __forceinline__ void gemm12b(i32x4 rsrc, const float* wl,
                                        const float* bias_l, float* dst,
                                        float* red, int tid) {
    const int bq = tid & 15, kq = tid >> 4;
    const int wv = tid >> 6, ln = tid & 63;
    int voff = ((kq << 6) + (bq << 2)) << 2;
    const float* wp = wl + kq * 12;
    f32x4 acc[12];
    #pragma unroll
    for (int c = 0; c < 12; ++c) acc[c] = (f32x4){0.f,0.f,0.f,0.f};
    #pragma unroll 8
    for (int i = 0; i < 32; ++i) {
        f32x4 a = llvm_amdgcn_raw_buffer_load_v4f32(rsrc, voff, 0, 16);
        voff += 32 * 64 * 4;
        f32x4 w0 = *(const f32x4*)(wp + 0);
        f32x4 w1 = *(const f32x4*)(wp + 4);
        f32x4 w2 = *(const f32x4*)(wp + 8);  wp += 32 * 12;
        F4(acc[0],w0.x) F4(acc[1],w0.y) F4(acc[2],w0.z)  F4(acc[3],w0.w)
        F4(acc[4],w1.x) F4(acc[5],w1.y) F4(acc[6],w1.z)  F4(acc[7],w1.w)
        F4(acc[8],w2.x) F4(acc[9],w2.y) F4(acc[10],w2.z) F4(acc[11],w2.w)
    }
    #pragma unroll
    for (int c = 0; c < 12; ++c) {
        f32x4 v = acc[c];
        v.x += __shfl_xor(v.x,16); v.y += __shfl_xor(v.y,16);
        v.z += __shfl_xor(v.z,16); v.w += __shfl_xor(v.w,16);
        v.x += __shfl_xor(v.x,32); v.y += __shfl_xor(v.y,32);
        v.z += __shfl_xor(v.z,32); v.w += __shfl_xor(v.w,32);
        if (ln < 16) *(f32x4*)&red[(wv * 12 + c) * 64 + (ln << 2)] = v;
    }
    __syncthreads();
    for (int o = tid; o < 768; o += NTHR) {
        int c = o >> 6, b = o & 63;
        float s = bias_l[c];
        #pragma unroll
        for (int w = 0; w < 8; ++w) s += red[(w * 12 + c) * 64 + b];
        dst[o] = s;
    }
}

// NC-col slice (cols C0..C0+NC-1), K=512 plain loads — bit-identical per-col
// to gemm12n; used to split gi across the two barrier-hidden slots.
template<int NC, int C0>
__device__ __forceinline__ void gemmN(const float* __restrict__ src,
                                      const float* wl,
                                      const float* bias_l, float* dst,
                                      float* red, int tid) {
    const int bq = tid & 15, kq = tid >> 4;
    const int wv = tid >> 6, ln = tid & 63;
    const float* ap = src + (kq << 6) + (bq << 2);
    const float* wp = wl + kq * 12 + C0;
    f32x4 acc[NC];
    #pragma unroll
    for (int c = 0; c < NC; ++c) acc[c] = (f32x4){0.f,0.f,0.f,0.f};
    #pragma unroll 4
    for (int i = 0; i < 16; ++i) {
        f32x4 a = *(const f32x4*)ap;  ap += 32 * 64;
        #pragma unroll
        for (int g = 0; g < NC / 4; ++g) {
            f32x4 w = *(const f32x4*)(wp + 4 * g);
            F4(acc[4*g+0],w.x) F4(acc[4*g+1],w.y) F4(acc[4*g+2],w.z) F4(acc[4*g+3],w.w)
        }
        wp += 32 * 12;
    }
    #pragma unroll
    for (int c = 0; c < NC; ++c) {
        f32x4 v = acc[c];
        v.x += __shfl_xor(v.x,16); v.y += __shfl_xor(v.y,16);
        v.z += __shfl_xor(v.z,16); v.w += __shfl_xor(v.w,16);
        v.x += __shfl_xor(v.x,32); v.y += __shfl_xor(v.y,32);
        v.z += __shfl_xor(v.z,32); v.w += __shfl_xor(v.w,32);
        if (ln < 16) *(f32x4*)&red[(wv * NC + c) * 64 + (ln << 2)] = v;
    }
    __syncthreads();
    if (tid < NC * 64) {
        int c = tid >> 6, b = tid & 63;
        float s = bias_l[C0 + c];
        #pragma unroll
        for (int w = 0; w < 8; ++w) s += red[(w * NC + c) * 64 + b];
        dst[(C0 + c) * 64 + b] = s;
    }
}

// global barrier wait: wave 0 polls all 64 counters in parallel, __all exit
__device__ __forceinline__ void gbar_wait(int slot, int tid) {
    if (tid < 64) {
        for (;;) {
            unsigned c = __hip_atomic_load(&g_bar[slot][tid << 5],
                                           __ATOMIC_RELAXED, __HIP_MEMORY_SCOPE_AGENT);
            if (__all(c >= 4u)) break;
            __builtin_amdgcn_s_sleep(1);
        }
    }
    __syncthreads();
    asm volatile("" ::: "memory");
}

// ---------------- persistent recurrence kernel ------------------------------
// 256 blocks x 512 threads; block owns hidden cols j = 4*blk..+3.
// P1 h_hat | arrive A | gi cols 0-7 | wait A | P2 gh + gates | arrive B |
// out-write + gi cols 8-11 | wait B.
__launch_bounds__(NTHR, 1)
__global__ void skipgru_2ph(const float* __restrict__ Wlin, const float* __restrict__ Wih,
                            const float* __restrict__ bih,  const float* __restrict__ Whh,
                            const float* __restrict__ bhh,  float* __restrict__ out) {
    __shared__ float wA[H_ * 4];        // 16 KB [k][c<4]
    __shared__ float wB[H_ * 12];       // 48 KB [k][c<12]
    __shared__ float wX[IN_ * 12];      // 24 KB [k][c<12]
    __shared__ float red[8 * 12 * 64];  // 24 KB
    __shared__ float gh_l[12 * 64];
    __shared__ float gi_a[12 * 64];
    __shared__ float gi_b[12 * 64];
    __shared__ float hh_l[4 * 64];
    __shared__ float hn_l[4 * 64];
    __shared__ float zp_l[4 * 64];
    __shared__ float bhh_l[12];
    __shared__ float bih_l[12];

    const int tid = threadIdx.x;
    const int jb  = blockIdx.x << 2;
    const int bq  = tid & 15;
    const int kq  = tid >> 4;
    const int wv  = tid >> 6, ln = tid & 63;
    const int barctr = (blockIdx.x & 63) << 5;   // 64 counters, 128 B apart

    for (int c = 0; c < 4; ++c) {
        const float* src = Wlin + (size_t)(jb + c) * WLK_;
        for (int k = tid; k < H_; k += NTHR) wA[k * 4 + c] = src[k];
    }
    for (int c = 0; c < 12; ++c) {
        const float* src = Whh + (size_t)((c >> 2) * H_ + jb + (c & 3)) * H_;
        for (int k = tid; k < H_; k += NTHR) wB[k * 12 + c] = src[k];
    }
    for (int c = 0; c < 12; ++c) {
        const float* src = Wih + (size_t)((c >> 2) * H_ + jb + (c & 3)) * IN_;
        for (int k = tid; k < IN_; k += NTHR) wX[k * 12 + c] = src[k];
    }
    if (tid < 256) zp_l[tid] = g_zprojT[(jb + (tid >> 6)) * 64 + (tid & 63)];
    if (tid < 12) {
        bhh_l[tid] = bhh[(tid >> 2) * H_ + jb + (tid & 3)];
        bih_l[tid] = bih[(tid >> 2) * H_ + jb + (tid & 3)];
    }
    __syncthreads();

    gemm12n(g_xT, wX, bih_l, gi_a, red, tid);
    __syncthreads();

    const i32x4 rs_hhat = mkrsrc(g_hhatT);
    const i32x4 rs_h0   = mkrsrc(g_h0T);
    const i32x4 rs_ha   = mkrsrc(g_hT[0]);
    const i32x4 rs_hb   = mkrsrc(g_hT[1]);

    for (int t = 0; t < S_; ++t) {
        const i32x4 rs_h = (t == 0) ? rs_h0 : ((t & 1) ? rs_hb : rs_ha);
        const float* gi_cur = (t & 1) ? gi_b : gi_a;
        float*       gi_nxt = (t & 1) ? gi_a : gi_b;
        const float* xnxt = g_xT + (size_t)(t + 1) * IN_ * B_;

        // ---- P1: h_hat, 4 cols, K=1024 (16B sc1 coherent loads, unroll 8) ----
        {
            int voff = ((kq << 6) + (bq << 2)) << 2;
            const float* wp = wA + kq * 4;
            f32x4 acc[4];
            #pragma unroll
            for (int c = 0; c < 4; ++c) acc[c] = (f32x4){0.f,0.f,0.f,0.f};
            #pragma unroll 8
            for (int i = 0; i < 32; ++i) {
                f32x4 a = llvm_amdgcn_raw_buffer_load_v4f32(rs_h, voff, 0, 16);
                voff += 8192;
                f32x4 w = *(const f32x4*)wp;  wp += 32 * 4;
                F4(acc[0],w.x) F4(acc[1],w.y) F4(acc[2],w.z) F4(acc[3],w.w)
            }
            #pragma unroll
            for (int c = 0; c < 4; ++c) {
                f32x4 v = acc[c];
                v.x += __shfl_xor(v.x,16); v.y += __shfl_xor(v.y,16);
                v.z += __shfl_xor(v.z,16); v.w += __shfl_xor(v.w,16);
                v.x += __shfl_xor(v.x,32); v.y += __shfl_xor(v.y,32);
                v.z += __shfl_xor(v.z,32); v.w += __shfl_xor(v.w,32);
                if (ln < 16) *(f32x4*)&red[(wv * 4 + c) * 64 + (ln << 2)] = v;
            }
        }
        __syncthreads();
        if (tid < 256) {
            int c = tid >> 6, b = tid & 63;
            float s = zp_l[tid];
            #pragma unroll
            for (int w = 0; w < 8; ++w) s += red[(w * 4 + c) * 64 + b];
            hh_l[tid] = s;
        }
        __syncthreads();
        if (tid < 128) {
            int c = tid >> 5, pb = (tid & 31) << 1;
            coh_store2(&g_hhatT[(jb + c) * 64 + pb], hh_l[(c << 6) + pb], hh_l[(c << 6) + pb + 1]);
        }
        __syncthreads();   // vmcnt(0) drain: h_hat publish complete before arrive

        // ---- arrive A ----
        if (tid == 0)
            __hip_atomic_fetch_add(&g_bar[2 * t][barctr], 1u, __ATOMIC_RELAXED, __HIP_MEMORY_SCOPE_AGENT);

        // ---- gi(t+1) cols 0-7, hidden under barrier A ----
        if (t + 1 < S_)
            gemmN<8, 0>(xnxt, wX, bih_l, gi_nxt, red, tid);

        // ---- wait A ----
        gbar_wait(2 * t, tid);

        // ---- P2: gh, 12 cols over h_hat, K=1024 (16B sc1, unroll 8) ----
        gemm12b(rs_hhat, wB, bhh_l, gh_l, red, tid);
        __syncthreads();

        // ---- gates (threads 0..255) ----
        if (tid < 256) {
            int cc = tid >> 6, b = tid & 63;
            float hh = hh_l[tid];
            float hr = gh_l[cc * 64 + b];
            float hz = gh_l[(4 + cc) * 64 + b];
            float hn = gh_l[(8 + cc) * 64 + b];
            float ir = gi_cur[cc * 64 + b];
            float iz = gi_cur[(4 + cc) * 64 + b];
            float in_ = gi_cur[(8 + cc) * 64 + b];
            float r = 1.f / (1.f + expf(-(ir + hr)));
            float u = 1.f / (1.f + expf(-(iz + hz)));
            float n = tanhf(in_ + r * hn);
            float v = (1.f - u) * n + u * hh;
            hn_l[tid] = v;
        }
        __syncthreads();
        if (tid < 128) {
            int c = tid >> 5, pb = (tid & 31) << 1;
            coh_store2(&g_hT[(t + 1) & 1][(jb + c) * 64 + pb], hn_l[(c << 6) + pb], hn_l[(c << 6) + pb + 1]);
        }
        __syncthreads();   // vmcnt(0) drain: h publish complete before arrive

        // ---- arrive B ----
        if (tid == 0)
            __hip_atomic_fetch_add(&g_bar[2 * t + 1][barctr], 1u, __ATOMIC_RELAXED, __HIP_MEMORY_SCOPE_AGENT);

        // ---- out write + gi(t+1) cols 8-11, hidden under barrier B ----
        if (tid < 256) {
            int cc = tid >> 6, b = tid & 63;
            int j = jb + cc;
            float v = hn_l[tid];
            out[((size_t)b * S_ + t) * H_ + j] = v;
            if (t == S_ - 1)
                out[(size_t)B_ * S_ * H_ + (size_t)b * H_ + j] = v;
        }
        if (t + 1 < S_)
            gemmN<4, 8>(xnxt, wX, bih_l, gi_nxt, red, tid);

        // ---- wait B ----
        gbar_wait(2 * t + 1, tid);
    }
}

extern "C" void kernel_launch(void* const* d_in, const int* in_sizes, int n_in,
                              void* d_out, int out_size, void* d_ws, size_t ws_size,
                              hipStream_t stream) {
    const float* inputs = (const float*)d_in[0];
    const float* h0     = (const float*)d_in[1];
    const float* z      = (const float*)d_in[2];
    const float* Wlin   = (const float*)d_in[3];
    const float* blin   = (const float*)d_in[4];
    const float* Wih    = (const float*)d_in[5];
    const float* bih    = (const float*)d_in[6];
    const float* Whh    = (const float*)d_in[7];
    const float* bhh    = (const float*)d_in[8];
    float* out = (float*)d_out;

    hipLaunchKernelGGL(pre_transpose_x, dim3(S_ * 8), dim3(256), 0, stream, inputs);
    hipLaunchKernelGGL(pre_misc, dim3(H_), dim3(64), 0, stream, z, Wlin, blin, h0);
    hipLaunchKernelGGL(skipgru_2ph, dim3(NBLK), dim3(NTHR), 0, stream,
                       Wlin, Wih, bih, Whh, bhh, out);
}